// Round 3
// baseline (354.086 us; speedup 1.0000x reference)
//
#include <hip/hip_runtime.h>
#include <cstdint>
#include <cstddef>

typedef _Float16 f16;
typedef _Float16 f16x8 __attribute__((ext_vector_type(8)));
typedef _Float16 f16x4 __attribute__((ext_vector_type(4)));
typedef float    f32x4 __attribute__((ext_vector_type(4)));

#define S_CTX 2048
#define NH 16
#define DH 128

__device__ __forceinline__ void gload16(const void* g, void* l) {
  __builtin_amdgcn_global_load_lds(
      (const __attribute__((address_space(1))) void*)g,
      (__attribute__((address_space(3))) void*)l, 16, 0, 0);
}

// ---------- prep: rope tables + x->f16 + 4x weight transpose, one dispatch ----------
// grid: [0,512) rope_tab | [512,8704) cvt | [8704,25088) wtrans (4 x 64 x 64)
__global__ void prep(const float* __restrict__ x,
                     const float* __restrict__ w0, const float* __restrict__ w1,
                     const float* __restrict__ w2, const float* __restrict__ w3,
                     f16* __restrict__ xb,
                     f16* __restrict__ o0, f16* __restrict__ o1,
                     f16* __restrict__ o2, f16* __restrict__ o3,
                     float* __restrict__ sint, float* __restrict__ cost) {
  const int bid = blockIdx.x, tid = threadIdx.x;
  if (bid < 512) {                       // rope tables: 2048*64
    int idx = bid * 256 + tid;
    int j = idx & 63, s = idx >> 6;
    float invf = __expf(-(float)(2 * j) * (1.0f / 128.0f) * 9.210340371976184f);
    float a = (float)s * invf;
    sint[idx] = sinf(a);
    cost[idx] = cosf(a);
  } else if (bid < 8704) {               // x fp32 -> fp16, 4 elems/thread
    int i = ((bid - 512) * 256 + tid) * 4;
    float4 v = *(const float4*)(x + i);
    f16x4 o; o[0] = (f16)v.x; o[1] = (f16)v.y; o[2] = (f16)v.z; o[3] = (f16)v.w;
    *(f16x4*)(xb + i) = o;
  } else {                               // W[k][n] fp32 -> Wt[n][k] fp16
    int b2 = bid - 8704;
    int z = b2 >> 12, rem = b2 & 4095;
    int by = rem >> 6, bx = rem & 63;
    int tx = tid & 31, ty = tid >> 5;    // (32,8)
    const float* in; f16* out;
    switch (z) {
      case 0: in = w0; out = o0; break;
      case 1: in = w1; out = o1; break;
      case 2: in = w2; out = o2; break;
      default: in = w3; out = o3; break;
    }
    __shared__ float tl[32][33];
    int xc = bx * 32 + tx, yc = by * 32 + ty;
#pragma unroll
    for (int r = 0; r < 32; r += 8)
      tl[ty + r][tx] = in[(size_t)(yc + r) * 2048 + xc];
    __syncthreads();
    int xo = by * 32 + tx, yo = bx * 32 + ty;
#pragma unroll
    for (int r = 0; r < 32; r += 8)
      out[(size_t)(yo + r) * 2048 + xo] = (f16)tl[tx][ty + r];
  }
}

// ---------- shared GEMM mainloop: 128x128 tile, BK=64, 4 waves ----------
// LDS tiles As/Bs: [128 rows][64 f16], 8 x 16B slots/row, swizzle slot ^= row&7.
// Column-fragment mapping: colf(wn,j) = wn*32 + (j&1)*16 + (j>>1)*64
// (so RoPE pairs (d, d+64) are acc[i][j] / acc[i][j+2] in the SAME wave).
__device__ __forceinline__ void gemm_mainloop(
    const f16* __restrict__ A, const f16* __restrict__ Bt,
    int row0, int col0, f16* As, f16* Bs, f32x4 (&acc)[4][4], int tid) {
  const int lane = tid & 63;
  const int wvi = tid >> 6;
  const int wm = wvi >> 1, wn = wvi & 1;
  const int rA0 = wm * 64 + (lane & 15);
  const int ls = lane >> 4;

  // staging: c = tid + j*256 -> row = c>>3, dest slot = c&7, src slot = (c&7)^(row&7)
  const int r_c[4] = { (tid) >> 3, (tid + 256) >> 3, (tid + 512) >> 3, (tid + 768) >> 3 };
  const f16* Ag[4]; const f16* Bg[4];
#pragma unroll
  for (int j = 0; j < 4; j++) {
    int c = tid + j * 256;
    int row = c >> 3, sl = (c & 7) ^ (row & 7);
    Ag[j] = A + (size_t)(row0 + row) * 2048 + sl * 8;
    Bg[j] = Bt + (size_t)(col0 + row) * 2048 + sl * 8;
  }
  (void)r_c;

  for (int k0 = 0; k0 < 2048; k0 += 64) {
    __syncthreads();
#pragma unroll
    for (int j = 0; j < 4; j++) {
      int c = tid + j * 256;
      gload16(Ag[j] + k0, As + c * 8);
      gload16(Bg[j] + k0, Bs + c * 8);
    }
    __syncthreads();
    f16x8 af[2][4], bf[2][4];
#pragma unroll
    for (int i = 0; i < 4; i++) {
      int rA = rA0 + i * 16;
#pragma unroll
      for (int kk = 0; kk < 2; kk++)
        af[kk][i] = *(const f16x8*)&As[rA * 64 + (((kk * 4 + ls) ^ (rA & 7)) << 3)];
    }
#pragma unroll
    for (int j = 0; j < 4; j++) {
      int rB = wn * 32 + (j & 1) * 16 + (j >> 1) * 64 + (lane & 15);
#pragma unroll
      for (int kk = 0; kk < 2; kk++)
        bf[kk][j] = *(const f16x8*)&Bs[rB * 64 + (((kk * 4 + ls) ^ (rB & 7)) << 3)];
    }
#pragma unroll
    for (int kk = 0; kk < 2; kk++)
#pragma unroll
      for (int i = 0; i < 4; i++)
#pragma unroll
        for (int j = 0; j < 4; j++)
          acc[i][j] = __builtin_amdgcn_mfma_f32_16x16x32_f16(af[kk][i], bf[kk][j], acc[i][j], 0, 0, 0);
  }
}

// ---------- fused QKV projection GEMM (+RoPE on Q,K; V^T epilogue) ----------
// grid (48, 32): blockIdx.x*128 in [0,6144); proj = >>11; col0 = &2047 (one head/block).
__global__ __launch_bounds__(256)
void gemm_qkv(const f16* __restrict__ A,
              const f16* __restrict__ wq, const f16* __restrict__ wk, const f16* __restrict__ wv,
              f16* __restrict__ qb, f16* __restrict__ kb, f16* __restrict__ vtb,
              const float* __restrict__ sint, const float* __restrict__ cost) {
  __shared__ __align__(16) f16 smem[2 * 128 * 64];
  f16* As = smem;
  f16* Bs = smem + 128 * 64;
  const int tid = threadIdx.x, lane = tid & 63;
  const int wvi = tid >> 6, wm = wvi >> 1, wn = wvi & 1;
  const int gcol = blockIdx.x * 128;
  const int proj = gcol >> 11;
  const int col0 = gcol & 2047;
  const int row0 = blockIdx.y * 128;
  const int h = col0 >> 7;

  const f16* Bt = (proj == 0) ? wq : ((proj == 1) ? wk : wv);
  f32x4 acc[4][4] = {};
  gemm_mainloop(A, Bt, row0, col0, As, Bs, acc, tid);

  if (proj < 2) {
    // Q/K epilogue with fused RoPE. d = wn*32 + jj*16 + (lane&15) in [0,64); pair d+64.
    f16* dst = proj ? kb : qb;
#pragma unroll
    for (int i = 0; i < 4; i++)
#pragma unroll
      for (int jj = 0; jj < 2; jj++)
#pragma unroll
        for (int r = 0; r < 4; r++) {
          int rowg = row0 + wm * 64 + i * 16 + (lane >> 4) * 4 + r;
          int b = rowg >> 11, s = rowg & 2047;
          int d = wn * 32 + jj * 16 + (lane & 15);
          float cv = cost[s * 64 + d], sv = sint[s * 64 + d];
          float x1 = acc[i][jj][r], x2 = acc[i][jj + 2][r];
          size_t base = ((size_t)(b * NH + h) * S_CTX + s) << 7;
          dst[base + d]      = (f16)(x1 * cv - x2 * sv);
          dst[base + d + 64] = (f16)(x2 * cv + x1 * sv);
        }
  } else {
    // V^T epilogue: write [b,h,d,s]
    const int b = row0 >> 11, s0 = row0 & 2047;
    f16* T = As;  // [64][130] padded, 16.6 KB
    for (int hh = 0; hh < 2; hh++) {
      __syncthreads();
      if (wm == hh) {
#pragma unroll
        for (int i = 0; i < 4; i++)
#pragma unroll
          for (int j = 0; j < 4; j++)
#pragma unroll
            for (int r = 0; r < 4; r++) {
              int rl = i * 16 + (lane >> 4) * 4 + r;                      // s-local
              int cl = wn * 32 + (j & 1) * 16 + (j >> 1) * 64 + (lane & 15); // d
              T[rl * 130 + cl] = (f16)acc[i][j][r];
            }
      }
      __syncthreads();
#pragma unroll
      for (int cc = 0; cc < 4; cc++) {
        int c = tid + cc * 256;
        int d = c >> 3, sc8 = (c & 7) * 8;
        f16x8 v;
#pragma unroll
        for (int e = 0; e < 8; e++) v[e] = T[(sc8 + e) * 130 + d];
        *(f16x8*)&vtb[((size_t)(b * NH + h) * DH + d) * S_CTX + s0 + hh * 64 + sc8] = v;
      }
    }
  }
}

// ---------- out-projection GEMM -> fp32 ----------
__global__ __launch_bounds__(256)
void gemm_out(const f16* __restrict__ A, const f16* __restrict__ Bt,
              float* __restrict__ of) {
  __shared__ __align__(16) f16 smem[2 * 128 * 64];
  f16* As = smem;
  f16* Bs = smem + 128 * 64;
  const int tid = threadIdx.x, lane = tid & 63;
  const int wvi = tid >> 6, wm = wvi >> 1, wn = wvi & 1;
  const int row0 = blockIdx.y * 128;
  const int col0 = blockIdx.x * 128;

  f32x4 acc[4][4] = {};
  gemm_mainloop(A, Bt, row0, col0, As, Bs, acc, tid);

#pragma unroll
  for (int i = 0; i < 4; i++)
#pragma unroll
    for (int j = 0; j < 4; j++)
#pragma unroll
      for (int r = 0; r < 4; r++) {
        int row = row0 + wm * 64 + i * 16 + (lane >> 4) * 4 + r;
        int col = col0 + wn * 32 + (j & 1) * 16 + (j >> 1) * 64 + (lane & 15);
        of[(size_t)row * 2048 + col] = acc[i][j][r];
      }
}

// ---------- flash attention, causal, no score scaling ----------
// grid: (16 tile-pairs, 32 bh). Block: 4 waves, each owns 16 q rows. KVBLK=64.
// Block i handles qt=i then qt=31-i -> every block does exactly 33 KV iterations.
__global__ __launch_bounds__(256)
void attn_k(const f16* __restrict__ q, const f16* __restrict__ kk,
            const f16* __restrict__ vt, f16* __restrict__ ctx) {
  __shared__ __align__(16) f16 Ks[64 * 128];   // [kv][d], slot ^= kv&7
  __shared__ __align__(16) f16 Vs[128 * 64];   // [d][kv], slot ^= d&7
  __shared__ __align__(16) f16 Pl[4][16 * 64]; // per wave [qr][kv], slot ^= qr&7
  const int tid = threadIdx.x, lane = tid & 63, wv = tid >> 6;
  const int bh = blockIdx.y;
  const int b = bh >> 4, h = bh & 15;
  const size_t plane = (size_t)bh * (S_CTX * DH);
  const f16* Qp = q + plane;
  const f16* Kp = kk + plane;
  const f16* Vp = vt + plane;
  const float LOG2E = 1.4426950408889634f;

  for (int half = 0; half < 2; half++) {
    const int qt = half ? (31 - (int)blockIdx.x) : (int)blockIdx.x;
    const int q0 = qt * 64;

    // Q fragments, pre-scaled by log2(e) so softmax runs in exp2 domain
    f16x8 qf[4];
    {
      const f16* qq = Qp + (size_t)(q0 + wv * 16 + (lane & 15)) * DH + ((lane >> 4) * 8);
#pragma unroll
      for (int ks = 0; ks < 4; ks++) {
        qf[ks] = *(const f16x8*)(qq + ks * 32);
#pragma unroll
        for (int e = 0; e < 8; e++) qf[ks][e] = (f16)((float)qf[ks][e] * LOG2E);
      }
    }
    float m_[4], l_[4];
    f32x4 o[8] = {};
#pragma unroll
    for (int r = 0; r < 4; r++) { m_[r] = -3e38f; l_[r] = 0.f; }

    for (int t = 0; t <= qt; t++) {
      __syncthreads();
#pragma unroll
      for (int j = 0; j < 4; j++) {
        int c = tid + j * 256;
        int row = c >> 4, sl = (c & 15) ^ (row & 7);
        gload16(Kp + (size_t)(t * 64 + row) * DH + sl * 8, Ks + c * 8);
      }
#pragma unroll
      for (int j = 0; j < 4; j++) {
        int c = tid + j * 256;
        int row = c >> 3, sl = (c & 7) ^ (row & 7);
        gload16(Vp + (size_t)row * S_CTX + t * 64 + sl * 8, Vs + c * 8);
      }
      __syncthreads();

      // S = Q K^T  (log2-units)
      f32x4 st[4] = {};
#pragma unroll
      for (int n = 0; n < 4; n++) {
        int rK = n * 16 + (lane & 15);
#pragma unroll
        for (int ks = 0; ks < 4; ks++) {
          int slot = ks * 4 + (lane >> 4);
          f16x8 kf = *(const f16x8*)&Ks[rK * 128 + ((slot ^ (rK & 7)) << 3)];
          st[n] = __builtin_amdgcn_mfma_f32_16x16x32_f16(qf[ks], kf, st[n], 0, 0, 0);
        }
      }
      if (t == qt) {
#pragma unroll
        for (int n = 0; n < 4; n++)
#pragma unroll
          for (int r = 0; r < 4; r++) {
            int kvc = n * 16 + (lane & 15);
            int qr = wv * 16 + (lane >> 4) * 4 + r;
            if (kvc > qr) st[n][r] = -3e38f;
          }
      }
      // online softmax
      float mx[4];
#pragma unroll
      for (int r = 0; r < 4; r++)
        mx[r] = fmaxf(fmaxf(st[0][r], st[1][r]), fmaxf(st[2][r], st[3][r]));
#pragma unroll
      for (int msk = 1; msk < 16; msk <<= 1)
#pragma unroll
        for (int r = 0; r < 4; r++) mx[r] = fmaxf(mx[r], __shfl_xor(mx[r], msk));
      bool need = false;
#pragma unroll
      for (int r = 0; r < 4; r++) need = need || (mx[r] > m_[r] + 8.0f);
      if (__any(need)) {
#pragma unroll
        for (int r = 0; r < 4; r++) {
          float nm = fmaxf(m_[r], mx[r]);
          float al = __builtin_amdgcn_exp2f(m_[r] - nm);
          m_[r] = nm;
          l_[r] *= al;
#pragma unroll
          for (int j = 0; j < 8; j++) o[j][r] *= al;
        }
      }
      float ps[4] = {0.f, 0.f, 0.f, 0.f};
      float pvv[4][4];
#pragma unroll
      for (int n = 0; n < 4; n++)
#pragma unroll
        for (int r = 0; r < 4; r++) {
          float p = __builtin_amdgcn_exp2f(st[n][r] - m_[r]);
          pvv[n][r] = p; ps[r] += p;
        }
#pragma unroll
      for (int msk = 1; msk < 16; msk <<= 1)
#pragma unroll
        for (int r = 0; r < 4; r++) ps[r] += __shfl_xor(ps[r], msk);
#pragma unroll
      for (int r = 0; r < 4; r++) l_[r] += ps[r];

      // P -> LDS (C-layout -> A-frag layout)
      f16* Pw = Pl[wv];
#pragma unroll
      for (int n = 0; n < 4; n++)
#pragma unroll
        for (int r = 0; r < 4; r++) {
          int rowp = (lane >> 4) * 4 + r;
          int colp = n * 16 + (lane & 15);
          Pw[rowp * 64 + (((colp >> 3) ^ (rowp & 7)) << 3) + (colp & 7)] = (f16)pvv[n][r];
        }
      // O += P V
#pragma unroll
      for (int ks = 0; ks < 2; ks++) {
        int rowp = lane & 15;
        int slotp = ks * 4 + (lane >> 4);
        f16x8 pa = *(const f16x8*)&Pw[rowp * 64 + ((slotp ^ (rowp & 7)) << 3)];
#pragma unroll
        for (int j = 0; j < 8; j++) {
          int rv = j * 16 + (lane & 15);
          int slotv = ks * 4 + (lane >> 4);
          f16x8 vf = *(const f16x8*)&Vs[rv * 64 + ((slotv ^ (rv & 7)) << 3)];
          o[j] = __builtin_amdgcn_mfma_f32_16x16x32_f16(pa, vf, o[j], 0, 0, 0);
        }
      }
    }

#pragma unroll
    for (int j = 0; j < 8; j++)
#pragma unroll
      for (int r = 0; r < 4; r++) {
        int qr = q0 + wv * 16 + (lane >> 4) * 4 + r;
        int dd = h * 128 + j * 16 + (lane & 15);
        ctx[((size_t)(b * S_CTX + qr) * 2048) + dd] = (f16)(o[j][r] / l_[r]);
      }
  }
}

extern "C" void kernel_launch(void* const* d_in, const int* in_sizes, int n_in,
                              void* d_out, int out_size, void* d_ws, size_t ws_size,
                              hipStream_t stream) {
  (void)in_sizes; (void)n_in; (void)out_size; (void)ws_size;
  const float* x  = (const float*)d_in[0];
  const float* Wq = (const float*)d_in[1];
  const float* Wk = (const float*)d_in[2];
  const float* Wv = (const float*)d_in[3];
  const float* Wo = (const float*)d_in[4];
  float* out = (float*)d_out;
  char* ws = (char*)d_ws;

  // layout (bytes); ctx aliases xb (xb dead after QKV projection)
  f16*   xb   = (f16*)(ws);                    // 16,777,216   x fp16 [4096][2048]
  f16*   ctxb = (f16*)(ws);                    // reuse
  f16*   wqT  = (f16*)(ws + 16777216);         // 8,388,608 each, [n][k] fp16
  f16*   wkT  = (f16*)(ws + 25165824);
  f16*   wvT  = (f16*)(ws + 33554432);
  f16*   woT  = (f16*)(ws + 41943040);
  f16*   qb   = (f16*)(ws + 50331648);         // [b,h,s,d] fp16 (rope applied)
  f16*   kb   = (f16*)(ws + 67108864);
  f16*   vtb  = (f16*)(ws + 83886080);         // [b,h,d,s] fp16
  float* sint = (float*)(ws + 100663296);      // [2048][64]
  float* cost = (float*)(ws + 101187584);

  prep<<<dim3(25088), dim3(256), 0, stream>>>(x, Wq, Wk, Wv, Wo, xb,
                                              wqT, wkT, wvT, woT, sint, cost);
  gemm_qkv<<<dim3(48, 32), dim3(256), 0, stream>>>(xb, wqT, wkT, wvT,
                                                   qb, kb, vtb, sint, cost);
  attn_k<<<dim3(16, 32), dim3(256), 0, stream>>>(qb, kb, vtb, ctxb);
  gemm_out<<<dim3(16, 32), dim3(256), 0, stream>>>(ctxb, woT, out);
}

// Round 4
// 301.737 us; speedup vs baseline: 1.1735x; 1.1735x over previous
//
#include <hip/hip_runtime.h>
#include <cstdint>
#include <cstddef>

typedef _Float16 f16;
typedef _Float16 f16x8 __attribute__((ext_vector_type(8)));
typedef _Float16 f16x4 __attribute__((ext_vector_type(4)));
typedef float    f32x4 __attribute__((ext_vector_type(4)));

#define S_CTX 2048
#define NH 16
#define DH 128

#define BAR() asm volatile("s_barrier" ::: "memory")
#define VMW(n) asm volatile("s_waitcnt vmcnt(" #n ")" ::: "memory")

__device__ __forceinline__ void gload16(const void* g, void* l) {
  __builtin_amdgcn_global_load_lds(
      (const __attribute__((address_space(1))) void*)g,
      (__attribute__((address_space(3))) void*)l, 16, 0, 0);
}

// ---------- prep: rope tables + x->f16 + 4x weight transpose, one dispatch ----------
__global__ void prep(const float* __restrict__ x,
                     const float* __restrict__ w0, const float* __restrict__ w1,
                     const float* __restrict__ w2, const float* __restrict__ w3,
                     f16* __restrict__ xb,
                     f16* __restrict__ o0, f16* __restrict__ o1,
                     f16* __restrict__ o2, f16* __restrict__ o3,
                     float* __restrict__ sint, float* __restrict__ cost) {
  const int bid = blockIdx.x, tid = threadIdx.x;
  if (bid < 512) {                       // rope tables: 2048*64
    int idx = bid * 256 + tid;
    int j = idx & 63, s = idx >> 6;
    float invf = __expf(-(float)(2 * j) * (1.0f / 128.0f) * 9.210340371976184f);
    float a = (float)s * invf;
    sint[idx] = sinf(a);
    cost[idx] = cosf(a);
  } else if (bid < 8704) {               // x fp32 -> fp16
    int i = ((bid - 512) * 256 + tid) * 4;
    float4 v = *(const float4*)(x + i);
    f16x4 o; o[0] = (f16)v.x; o[1] = (f16)v.y; o[2] = (f16)v.z; o[3] = (f16)v.w;
    *(f16x4*)(xb + i) = o;
  } else {                               // W[k][n] fp32 -> Wt[n][k] fp16
    int b2 = bid - 8704;
    int z = b2 >> 12, rem = b2 & 4095;
    int by = rem >> 6, bx = rem & 63;
    int tx = tid & 31, ty = tid >> 5;
    const float* in; f16* out;
    switch (z) {
      case 0: in = w0; out = o0; break;
      case 1: in = w1; out = o1; break;
      case 2: in = w2; out = o2; break;
      default: in = w3; out = o3; break;
    }
    __shared__ float tl[32][33];
    int xc = bx * 32 + tx, yc = by * 32 + ty;
#pragma unroll
    for (int r = 0; r < 32; r += 8)
      tl[ty + r][tx] = in[(size_t)(yc + r) * 2048 + xc];
    __syncthreads();
    int xo = by * 32 + tx, yo = bx * 32 + ty;
#pragma unroll
    for (int r = 0; r < 32; r += 8)
      out[(size_t)(yo + r) * 2048 + xo] = (f16)tl[tx][ty + r];
  }
}

// ---------- 8-phase 256x256 fused QKV GEMM (+RoPE / V^T epilogues) ----------
// 512 thr = 8 waves (2M x 4N). K in halves of 32 (2 per BK=64 tile, 64 halves).
// LDS ring: 4 half-slots x (A[256][32] 16KB + B[256][32] 16KB) = 128 KB dynamic.
// Half h staged: A-pair at phase 2h-6, B-pair at 2h-5 (3 halves ahead).
// Counted vmcnt(8) at odd phases proves half (P+1)/2 landed; taper 8/4/0 at tail.
// LDS swizzle: 4x16B slots/row, slot ^= (row>>1)&3 (pre-swizzled global source).
__global__ __launch_bounds__(512, 1)
void gemm_qkv8(const f16* __restrict__ A,
               const f16* __restrict__ wq, const f16* __restrict__ wk, const f16* __restrict__ wv,
               f16* __restrict__ qb, f16* __restrict__ kb, f16* __restrict__ vtb,
               const float* __restrict__ sint, const float* __restrict__ cost) {
  extern __shared__ __align__(16) char lds[];
#define RING_A(e) (lds + (e) * 16384)
#define RING_B(e) (lds + 65536 + (e) * 16384)
  const int tid = threadIdx.x, lane = tid & 63;
  const int wvi = tid >> 6, wm = wvi >> 2, wn = wvi & 3;
  const int gcol = blockIdx.x * 256;
  const int proj = gcol >> 11;           // 0 q, 1 k, 2 v
  const int col0 = gcol & 2047;
  const int row0 = blockIdx.y * 256;
  const f16* Bt = (proj == 0) ? wq : ((proj == 1) ? wk : wv);

  // staging constants: A chunks {tid, tid+512}, B chunks {tid, tid+512}
  const int ca0 = tid, ca1 = tid + 512;
  const int raA0 = ca0 >> 2, raA1 = ca1 >> 2;
  const int swA0 = (ca0 & 3) ^ ((raA0 >> 1) & 3);
  const int swA1 = (ca1 & 3) ^ ((raA1 >> 1) & 3);
  const f16* gA0 = A + (size_t)(row0 + raA0) * 2048 + swA0 * 8;
  const f16* gA1 = A + (size_t)(row0 + raA1) * 2048 + swA1 * 8;
  const f16* gB0 = Bt + (size_t)(col0 + raA0) * 2048 + swA0 * 8;
  const f16* gB1 = Bt + (size_t)(col0 + raA1) * 2048 + swA1 * 8;

  // fragment read offsets (bytes within a 16KB half)
  const int kslot = lane >> 4;
  int aoff[8], boff[4];
#pragma unroll
  for (int i = 0; i < 8; i++) {
    int row = wm * 128 + i * 16 + (lane & 15);
    aoff[i] = row * 64 + ((kslot ^ ((row >> 1) & 3)) << 4);
  }
#pragma unroll
  for (int j = 0; j < 4; j++) {
    int rb = (wn >> 1) * 128 + (wn & 1) * 32 + (j & 1) * 16 + (j >> 1) * 64 + (lane & 15);
    boff[j] = rb * 64 + ((kslot ^ ((rb >> 1) & 3)) << 4);
  }

  f32x4 acc[8][4] = {};
  f16x8 bfc[4];

  // phase: ds-reads (B cached at mh==0) | stage | BARRIER | setprio+16 MFMA
  auto PH = [&](int e, int mh, int stagemat, int h) {
    const char* As_ = RING_A(e);
    const char* Bs_ = RING_B(e);
    f16x8 af[4];
#pragma unroll
    for (int ii = 0; ii < 4; ii++)
      af[ii] = *(const f16x8*)(As_ + aoff[mh * 4 + ii]);
    if (mh == 0) {
#pragma unroll
      for (int j = 0; j < 4; j++)
        bfc[j] = *(const f16x8*)(Bs_ + boff[j]);
    }
    if (stagemat == 0) {
      gload16(gA0 + h * 32, RING_A(h & 3) + ca0 * 16);
      gload16(gA1 + h * 32, RING_A(h & 3) + ca1 * 16);
    } else if (stagemat == 1) {
      gload16(gB0 + h * 32, RING_B(h & 3) + ca0 * 16);
      gload16(gB1 + h * 32, RING_B(h & 3) + ca1 * 16);
    }
    BAR();
    __builtin_amdgcn_s_setprio(1);
#pragma unroll
    for (int j = 0; j < 4; j++)
#pragma unroll
      for (int ii = 0; ii < 4; ii++)
        acc[mh * 4 + ii][j] =
            __builtin_amdgcn_mfma_f32_16x16x32_f16(af[ii], bfc[j], acc[mh * 4 + ii][j], 0, 0, 0);
    __builtin_amdgcn_s_setprio(0);
  };

  // prologue: stage halves 0,1,2
#pragma unroll
  for (int h = 0; h < 3; h++) {
    gload16(gA0 + h * 32, RING_A(h) + ca0 * 16);
    gload16(gA1 + h * 32, RING_A(h) + ca1 * 16);
    gload16(gB0 + h * 32, RING_B(h) + ca0 * 16);
    gload16(gB1 + h * 32, RING_B(h) + ca1 * 16);
  }
  VMW(8); BAR();

  for (int t = 0; t < 30; ++t) {
    int e0 = (2 * t) & 3, e1 = (2 * t + 1) & 3;
    PH(e0, 0, 0, 2 * t + 3);          BAR();
    PH(e0, 1, 1, 2 * t + 3); VMW(8);  BAR();
    PH(e1, 0, 0, 2 * t + 4);          BAR();
    PH(e1, 1, 1, 2 * t + 4); VMW(8);  BAR();
  }
  // t=30: stage only half 63
  PH(0, 0, 0, 63);          BAR();
  PH(0, 1, 1, 63); VMW(8);  BAR();
  PH(1, 0, 2, 0);           BAR();
  PH(1, 1, 2, 0);  VMW(4);  BAR();
  // t=31: no staging
  PH(2, 0, 2, 0);           BAR();
  PH(2, 1, 2, 0);  VMW(0);  BAR();
  PH(3, 0, 2, 0);           BAR();
  PH(3, 1, 2, 0);           BAR();

  const int b = row0 >> 11, sbase = row0 & 2047;

  if (proj < 2) {
    // RoPE epilogue: d = (wn&1)*32 + jj*16 + lane15 in [0,64); partner acc[i][jj+2]
    f16* dst = proj ? kb : qb;
#pragma unroll
    for (int i = 0; i < 8; i++)
#pragma unroll
      for (int jj = 0; jj < 2; jj++)
#pragma unroll
        for (int r = 0; r < 4; r++) {
          int s = sbase + wm * 128 + i * 16 + (lane >> 4) * 4 + r;
          int d = (wn & 1) * 32 + jj * 16 + (lane & 15);
          int h = (col0 >> 7) + (wn >> 1);
          float cv = cost[s * 64 + d], sv = sint[s * 64 + d];
          float x1 = acc[i][jj][r], x2 = acc[i][jj + 2][r];
          size_t base = ((size_t)(b * NH + h) * S_CTX + s) << 7;
          dst[base + d]      = (f16)(x1 * cv - x2 * sv);
          dst[base + d + 64] = (f16)(x2 * cv + x1 * sv);
        }
  } else {
    // V^T epilogue: transpose 256x256 through LDS (8B units, XOR swizzle)
    f16x4* ldsv = (f16x4*)lds;
#pragma unroll
    for (int i = 0; i < 8; i++)
#pragma unroll
      for (int j = 0; j < 4; j++) {
        f16x4 v;
#pragma unroll
        for (int r = 0; r < 4; r++) v[r] = (f16)acc[i][j][r];
        int col = (wn >> 1) * 128 + (wn & 1) * 32 + (j & 1) * 16 + (j >> 1) * 64 + (lane & 15);
        int su = wm * 32 + i * 4 + (lane >> 4);
        ldsv[col * 64 + (su ^ ((col << 1) & 63))] = v;
      }
    BAR();
#pragma unroll
    for (int it = 0; it < 16; ++it) {
      int o = it * 512 + tid;           // [0,8192): col = o>>5, s8 = o&31
      int col = o >> 5, s8 = o & 31;
      int xc = (col << 1) & 63;
      f16x4 lo = ldsv[col * 64 + ((s8 * 2) ^ xc)];
      f16x4 hi = ldsv[col * 64 + ((s8 * 2 + 1) ^ xc)];
      f16x8 vv;
      vv[0] = lo[0]; vv[1] = lo[1]; vv[2] = lo[2]; vv[3] = lo[3];
      vv[4] = hi[0]; vv[5] = hi[1]; vv[6] = hi[2]; vv[7] = hi[3];
      int h = (col0 >> 7) + (col >> 7), d = col & 127;
      *(f16x8*)&vtb[(((size_t)(b * NH + h) * DH + d) << 11) + sbase + s8 * 8] = vv;
    }
  }
#undef RING_A
#undef RING_B
}

// ---------- out-projection GEMM (R2-proven 2-barrier BK=32 128^2) ----------
__global__ __launch_bounds__(256)
void gemm_out(const f16* __restrict__ A, const f16* __restrict__ Bt,
              float* __restrict__ of) {
  __shared__ __align__(16) char smem[16384];
  f16* As = (f16*)smem;            // [128][32], slot ^= (row>>1)&3
  f16* Bs = (f16*)(smem + 8192);
  const int tid = threadIdx.x;
  const int lane = tid & 63;
  const int wvq = tid >> 6;
  const int wm = wvq >> 1, wn = wvq & 1;
  const int row0 = blockIdx.y * 128;
  const int col0 = blockIdx.x * 128;

  f32x4 acc[4][4] = {};

  const int c0 = tid, c1 = tid + 256;
  const int ra0 = c0 >> 2, sa0 = (c0 & 3) ^ ((ra0 >> 1) & 3);
  const int ra1 = c1 >> 2, sa1 = (c1 & 3) ^ ((ra1 >> 1) & 3);
  const f16* Ag0 = A + (size_t)(row0 + ra0) * 2048 + sa0 * 8;
  const f16* Ag1 = A + (size_t)(row0 + ra1) * 2048 + sa1 * 8;
  const f16* Bg0 = Bt + (size_t)(col0 + ra0) * 2048 + sa0 * 8;
  const f16* Bg1 = Bt + (size_t)(col0 + ra1) * 2048 + sa1 * 8;
  f16* Al0 = As + c0 * 8; f16* Al1 = As + c1 * 8;
  f16* Bl0 = Bs + c0 * 8; f16* Bl1 = Bs + c1 * 8;

  const int rA0 = wm * 64 + (lane & 15);
  const int rB0 = wn * 64 + (lane & 15);
  const int ls = lane >> 4;

  for (int k0 = 0; k0 < 2048; k0 += 32) {
    __syncthreads();
    gload16(Ag0 + k0, Al0);
    gload16(Ag1 + k0, Al1);
    gload16(Bg0 + k0, Bl0);
    gload16(Bg1 + k0, Bl1);
    __syncthreads();
    f16x8 af[4], bf[4];
#pragma unroll
    for (int i = 0; i < 4; i++) {
      int rA = rA0 + i * 16;
      int rB = rB0 + i * 16;
      af[i] = *(const f16x8*)&As[rA * 32 + ((ls ^ ((rA >> 1) & 3)) << 3)];
      bf[i] = *(const f16x8*)&Bs[rB * 32 + ((ls ^ ((rB >> 1) & 3)) << 3)];
    }
#pragma unroll
    for (int i = 0; i < 4; i++)
#pragma unroll
      for (int j = 0; j < 4; j++)
        acc[i][j] = __builtin_amdgcn_mfma_f32_16x16x32_f16(af[i], bf[j], acc[i][j], 0, 0, 0);
  }

#pragma unroll
  for (int i = 0; i < 4; i++)
#pragma unroll
    for (int j = 0; j < 4; j++)
#pragma unroll
      for (int r = 0; r < 4; r++) {
        int row = row0 + wm * 64 + i * 16 + (lane >> 4) * 4 + r;
        int col = col0 + wn * 64 + j * 16 + (lane & 15);
        of[(size_t)row * 2048 + col] = acc[i][j][r];
      }
}

// ---------- flash attention, causal, no score scaling ----------
__global__ __launch_bounds__(256)
void attn_k(const f16* __restrict__ q, const f16* __restrict__ kk,
            const f16* __restrict__ vt, f16* __restrict__ ctx) {
  __shared__ __align__(16) f16 Ks[64 * 128];   // [kv][d], slot ^= kv&7
  __shared__ __align__(16) f16 Vs[128 * 64];   // [d][kv], slot ^= d&7
  __shared__ __align__(16) f16 Pl[4][16 * 64]; // per wave [qr][kv], slot ^= qr&7
  const int tid = threadIdx.x, lane = tid & 63, wv = tid >> 6;
  const int bh = blockIdx.y;
  const int b = bh >> 4, h = bh & 15;
  const size_t plane = (size_t)bh * (S_CTX * DH);
  const f16* Qp = q + plane;
  const f16* Kp = kk + plane;
  const f16* Vp = vt + plane;
  const float LOG2E = 1.4426950408889634f;

  for (int half = 0; half < 2; half++) {
    const int qt = half ? (31 - (int)blockIdx.x) : (int)blockIdx.x;
    const int q0 = qt * 64;

    f16x8 qf[4];
    {
      const f16* qq = Qp + (size_t)(q0 + wv * 16 + (lane & 15)) * DH + ((lane >> 4) * 8);
#pragma unroll
      for (int ks = 0; ks < 4; ks++) {
        qf[ks] = *(const f16x8*)(qq + ks * 32);
#pragma unroll
        for (int e = 0; e < 8; e++) qf[ks][e] = (f16)((float)qf[ks][e] * LOG2E);
      }
    }
    float m_[4], l_[4];
    f32x4 o[8] = {};
#pragma unroll
    for (int r = 0; r < 4; r++) { m_[r] = -3e38f; l_[r] = 0.f; }

    for (int t = 0; t <= qt; t++) {
      __syncthreads();
#pragma unroll
      for (int j = 0; j < 4; j++) {
        int c = tid + j * 256;
        int row = c >> 4, sl = (c & 15) ^ (row & 7);
        gload16(Kp + (size_t)(t * 64 + row) * DH + sl * 8, Ks + c * 8);
      }
#pragma unroll
      for (int j = 0; j < 4; j++) {
        int c = tid + j * 256;
        int row = c >> 3, sl = (c & 7) ^ (row & 7);
        gload16(Vp + (size_t)row * S_CTX + t * 64 + sl * 8, Vs + c * 8);
      }
      __syncthreads();

      f32x4 st[4] = {};
#pragma unroll
      for (int n = 0; n < 4; n++) {
        int rK = n * 16 + (lane & 15);
#pragma unroll
        for (int ks = 0; ks < 4; ks++) {
          int slot = ks * 4 + (lane >> 4);
          f16x8 kf = *(const f16x8*)&Ks[rK * 128 + ((slot ^ (rK & 7)) << 3)];
          st[n] = __builtin_amdgcn_mfma_f32_16x16x32_f16(qf[ks], kf, st[n], 0, 0, 0);
        }
      }
      if (t == qt) {
#pragma unroll
        for (int n = 0; n < 4; n++)
#pragma unroll
          for (int r = 0; r < 4; r++) {
            int kvc = n * 16 + (lane & 15);
            int qr = wv * 16 + (lane >> 4) * 4 + r;
            if (kvc > qr) st[n][r] = -3e38f;
          }
      }
      float mx[4];
#pragma unroll
      for (int r = 0; r < 4; r++)
        mx[r] = fmaxf(fmaxf(st[0][r], st[1][r]), fmaxf(st[2][r], st[3][r]));
#pragma unroll
      for (int msk = 1; msk < 16; msk <<= 1)
#pragma unroll
        for (int r = 0; r < 4; r++) mx[r] = fmaxf(mx[r], __shfl_xor(mx[r], msk));
      bool need = false;
#pragma unroll
      for (int r = 0; r < 4; r++) need = need || (mx[r] > m_[r] + 8.0f);
      if (__any(need)) {
#pragma unroll
        for (int r = 0; r < 4; r++) {
          float nm = fmaxf(m_[r], mx[r]);
          float al = __builtin_amdgcn_exp2f(m_[r] - nm);
          m_[r] = nm;
          l_[r] *= al;
#pragma unroll
          for (int j = 0; j < 8; j++) o[j][r] *= al;
        }
      }
      float ps[4] = {0.f, 0.f, 0.f, 0.f};
      float pvv[4][4];
#pragma unroll
      for (int n = 0; n < 4; n++)
#pragma unroll
        for (int r = 0; r < 4; r++) {
          float p = __builtin_amdgcn_exp2f(st[n][r] - m_[r]);
          pvv[n][r] = p; ps[r] += p;
        }
#pragma unroll
      for (int msk = 1; msk < 16; msk <<= 1)
#pragma unroll
        for (int r = 0; r < 4; r++) ps[r] += __shfl_xor(ps[r], msk);
#pragma unroll
      for (int r = 0; r < 4; r++) l_[r] += ps[r];

      f16* Pw = Pl[wv];
#pragma unroll
      for (int n = 0; n < 4; n++)
#pragma unroll
        for (int r = 0; r < 4; r++) {
          int rowp = (lane >> 4) * 4 + r;
          int colp = n * 16 + (lane & 15);
          Pw[rowp * 64 + (((colp >> 3) ^ (rowp & 7)) << 3) + (colp & 7)] = (f16)pvv[n][r];
        }
#pragma unroll
      for (int ks = 0; ks < 2; ks++) {
        int rowp = lane & 15;
        int slotp = ks * 4 + (lane >> 4);
        f16x8 pa = *(const f16x8*)&Pw[rowp * 64 + ((slotp ^ (rowp & 7)) << 3)];
#pragma unroll
        for (int j = 0; j < 8; j++) {
          int rv = j * 16 + (lane & 15);
          int slotv = ks * 4 + (lane >> 4);
          f16x8 vf = *(const f16x8*)&Vs[rv * 64 + ((slotv ^ (rv & 7)) << 3)];
          o[j] = __builtin_amdgcn_mfma_f32_16x16x32_f16(pa, vf, o[j], 0, 0, 0);
        }
      }
    }

#pragma unroll
    for (int j = 0; j < 8; j++)
#pragma unroll
      for (int r = 0; r < 4; r++) {
        int qr = q0 + wv * 16 + (lane >> 4) * 4 + r;
        int dd = h * 128 + j * 16 + (lane & 15);
        ctx[((size_t)(b * S_CTX + qr) * 2048) + dd] = (f16)(o[j][r] / l_[r]);
      }
  }
}

extern "C" void kernel_launch(void* const* d_in, const int* in_sizes, int n_in,
                              void* d_out, int out_size, void* d_ws, size_t ws_size,
                              hipStream_t stream) {
  (void)in_sizes; (void)n_in; (void)out_size; (void)ws_size;
  const float* x  = (const float*)d_in[0];
  const float* Wq = (const float*)d_in[1];
  const float* Wk = (const float*)d_in[2];
  const float* Wv = (const float*)d_in[3];
  const float* Wo = (const float*)d_in[4];
  float* out = (float*)d_out;
  char* ws = (char*)d_ws;

  f16*   xb   = (f16*)(ws);                    // x fp16 [4096][2048]
  f16*   ctxb = (f16*)(ws);                    // reuse (xb dead after QKV)
  f16*   wqT  = (f16*)(ws + 16777216);         // [n][k] fp16, 8 MB each
  f16*   wkT  = (f16*)(ws + 25165824);
  f16*   wvT  = (f16*)(ws + 33554432);
  f16*   woT  = (f16*)(ws + 41943040);
  f16*   qb   = (f16*)(ws + 50331648);         // [b,h,s,d] fp16 (rope applied)
  f16*   kb   = (f16*)(ws + 67108864);
  f16*   vtb  = (f16*)(ws + 83886080);         // [b,h,d,s] fp16
  float* sint = (float*)(ws + 100663296);      // [2048][64]
  float* cost = (float*)(ws + 101187584);

  prep<<<dim3(25088), dim3(256), 0, stream>>>(x, Wq, Wk, Wv, Wo, xb,
                                              wqT, wkT, wvT, woT, sint, cost);
  gemm_qkv8<<<dim3(24, 16), dim3(512), 131072, stream>>>(xb, wqT, wkT, wvT,
                                                         qb, kb, vtb, sint, cost);
  attn_k<<<dim3(16, 32), dim3(256), 0, stream>>>(qb, kb, vtb, ctxb);
  gemm_out<<<dim3(16, 32), dim3(256), 0, stream>>>(ctxb, woT, out);
}

// Round 5
// 280.790 us; speedup vs baseline: 1.2610x; 1.0746x over previous
//
#include <hip/hip_runtime.h>
#include <cstdint>
#include <cstddef>

typedef _Float16 f16;
typedef _Float16 f16x8 __attribute__((ext_vector_type(8)));
typedef _Float16 f16x4 __attribute__((ext_vector_type(4)));
typedef float    f32x4 __attribute__((ext_vector_type(4)));

#define S_CTX 2048
#define NH 16
#define DH 128

#define BAR() asm volatile("s_barrier" ::: "memory")
#define VMW(n) asm volatile("s_waitcnt vmcnt(" #n ")" ::: "memory")

__device__ __forceinline__ void gload16(const void* g, void* l) {
  __builtin_amdgcn_global_load_lds(
      (const __attribute__((address_space(1))) void*)g,
      (__attribute__((address_space(3))) void*)l, 16, 0, 0);
}

// ---------- prep: rope tables + x->f16 + 4x weight transpose, one dispatch ----------
__global__ void prep(const float* __restrict__ x,
                     const float* __restrict__ w0, const float* __restrict__ w1,
                     const float* __restrict__ w2, const float* __restrict__ w3,
                     f16* __restrict__ xb,
                     f16* __restrict__ o0, f16* __restrict__ o1,
                     f16* __restrict__ o2, f16* __restrict__ o3,
                     float* __restrict__ sint, float* __restrict__ cost) {
  const int bid = blockIdx.x, tid = threadIdx.x;
  if (bid < 512) {                       // rope tables: 2048*64
    int idx = bid * 256 + tid;
    int j = idx & 63, s = idx >> 6;
    float invf = __expf(-(float)(2 * j) * (1.0f / 128.0f) * 9.210340371976184f);
    float a = (float)s * invf;
    sint[idx] = sinf(a);
    cost[idx] = cosf(a);
  } else if (bid < 8704) {               // x fp32 -> fp16
    int i = ((bid - 512) * 256 + tid) * 4;
    float4 v = *(const float4*)(x + i);
    f16x4 o; o[0] = (f16)v.x; o[1] = (f16)v.y; o[2] = (f16)v.z; o[3] = (f16)v.w;
    *(f16x4*)(xb + i) = o;
  } else {                               // W[k][n] fp32 -> Wt[n][k] fp16
    int b2 = bid - 8704;
    int z = b2 >> 12, rem = b2 & 4095;
    int by = rem >> 6, bx = rem & 63;
    int tx = tid & 31, ty = tid >> 5;
    const float* in; f16* out;
    switch (z) {
      case 0: in = w0; out = o0; break;
      case 1: in = w1; out = o1; break;
      case 2: in = w2; out = o2; break;
      default: in = w3; out = o3; break;
    }
    __shared__ float tl[32][33];
    int xc = bx * 32 + tx, yc = by * 32 + ty;
#pragma unroll
    for (int r = 0; r < 32; r += 8)
      tl[ty + r][tx] = in[(size_t)(yc + r) * 2048 + xc];
    __syncthreads();
    int xo = by * 32 + tx, yo = bx * 32 + ty;
#pragma unroll
    for (int r = 0; r < 32; r += 8)
      out[(size_t)(yo + r) * 2048 + xo] = (f16)tl[tx][ty + r];
  }
}

// ---------- 8-phase GEMM, tile 256x128, 8 waves (4M x 2N), per-wave 64x64 ----------
// K walked in halves of 32 (64 phases). LDS ring: 4 slots x (A[256][32] 16KB +
// B[128][32] 8KB) = 96 KB. 3 loads/thread/half (2A+1B), depth-3 prefetch,
// counted vmcnt(6) per phase (leaves h+2,h+3 in flight), taper 6/3/0/63.
// Row swizzle: 4x16B slots/row, slot ^= (row>>1)&3, pre-swizzled global source.
// Col map: col = wn*32 + (j&1)*16 + (j>>1)*64 (+lane&15) -> RoPE pair j/j+2 same wave.
// OUTP=false: QKV fused (grid 48x16=768=3 rounds; proj by gcol>>11; RoPE or V^T epi)
// OUTP=true : out-projection (grid 16x16=256=1 round; f32 epilogue)
template<bool OUTP>
__global__ __launch_bounds__(512, 1)
void gemm8(const f16* __restrict__ A,
           const f16* __restrict__ wq, const f16* __restrict__ wk, const f16* __restrict__ wv,
           f16* __restrict__ qb, f16* __restrict__ kb, f16* __restrict__ vtb,
           float* __restrict__ of,
           const float* __restrict__ sint, const float* __restrict__ cost) {
  extern __shared__ __align__(16) char lds[];
#define RING_A(e) (lds + (e) * 16384)
#define RING_B(e) (lds + 65536 + (e) * 8192)
  const int tid = threadIdx.x, lane = tid & 63;
  const int wvi = tid >> 6, wm = wvi >> 1, wn = wvi & 1;
  const int gcol = blockIdx.x * 128;
  const int proj = OUTP ? 0 : (gcol >> 11);
  const int col0 = OUTP ? gcol : (gcol & 2047);
  const int row0 = blockIdx.y * 256;
  const f16* Bt = OUTP ? wq : (proj == 0 ? wq : (proj == 1 ? wk : wv));

  // staging: A chunks {tid, tid+512} cover 256x32; B chunk {tid} covers 128x32
  const int ca0 = tid, ca1 = tid + 512, cb0 = tid;
  const int rAs0 = ca0 >> 2, rAs1 = ca1 >> 2, rBs0 = cb0 >> 2;
  const int sA0 = (ca0 & 3) ^ ((rAs0 >> 1) & 3);
  const int sA1 = (ca1 & 3) ^ ((rAs1 >> 1) & 3);
  const int sB0 = (cb0 & 3) ^ ((rBs0 >> 1) & 3);
  const f16* gA0 = A + (size_t)(row0 + rAs0) * 2048 + sA0 * 8;
  const f16* gA1 = A + (size_t)(row0 + rAs1) * 2048 + sA1 * 8;
  const f16* gB0 = Bt + (size_t)(col0 + rBs0) * 2048 + sB0 * 8;

  // fragment read byte-offsets within a slot
  const int kslot = lane >> 4;
  int aoff[4], boff[4];
#pragma unroll
  for (int i = 0; i < 4; i++) {
    int row = wm * 64 + i * 16 + (lane & 15);
    aoff[i] = row * 64 + ((kslot ^ ((row >> 1) & 3)) << 4);
  }
#pragma unroll
  for (int j = 0; j < 4; j++) {
    int rb = wn * 32 + (j & 1) * 16 + (j >> 1) * 64 + (lane & 15);
    boff[j] = rb * 64 + ((kslot ^ ((rb >> 1) & 3)) << 4);
  }

  f32x4 acc[4][4] = {};

#define PHASE(SLOT, HS, DOSTAGE, WN) do {                                      \
    const char* As_ = RING_A(SLOT);                                            \
    const char* Bs_ = RING_B(SLOT);                                            \
    f16x8 af[4], bf[4];                                                        \
    _Pragma("unroll") for (int i_ = 0; i_ < 4; i_++)                           \
      af[i_] = *(const f16x8*)(As_ + aoff[i_]);                                \
    _Pragma("unroll") for (int j_ = 0; j_ < 4; j_++)                           \
      bf[j_] = *(const f16x8*)(Bs_ + boff[j_]);                                \
    if (DOSTAGE) {                                                             \
      gload16(gA0 + (HS) * 32, RING_A((HS) & 3) + ca0 * 16);                   \
      gload16(gA1 + (HS) * 32, RING_A((HS) & 3) + ca1 * 16);                   \
      gload16(gB0 + (HS) * 32, RING_B((HS) & 3) + cb0 * 16);                   \
    }                                                                          \
    asm volatile("s_waitcnt vmcnt(" #WN ")" ::: "memory");                     \
    BAR();                                                                     \
    __builtin_amdgcn_s_setprio(1);                                             \
    _Pragma("unroll") for (int i_ = 0; i_ < 4; i_++)                           \
      _Pragma("unroll") for (int j_ = 0; j_ < 4; j_++)                         \
        acc[i_][j_] = __builtin_amdgcn_mfma_f32_16x16x32_f16(af[i_], bf[j_],   \
                                                             acc[i_][j_], 0, 0, 0); \
    __builtin_amdgcn_s_setprio(0);                                             \
    BAR();                                                                     \
  } while (0)

  // prologue: stage halves 0,1,2 (9 loads); vmcnt(6) -> half 0 landed
#pragma unroll
  for (int h = 0; h < 3; h++) {
    gload16(gA0 + h * 32, RING_A(h) + ca0 * 16);
    gload16(gA1 + h * 32, RING_A(h) + ca1 * 16);
    gload16(gB0 + h * 32, RING_B(h) + cb0 * 16);
  }
  VMW(6); BAR();

  for (int t = 0; t < 15; ++t) {
    const int p = t * 4;
    PHASE(0, p + 3, 1, 6);
    PHASE(1, p + 4, 1, 6);
    PHASE(2, p + 5, 1, 6);
    PHASE(3, p + 6, 1, 6);
  }
  PHASE(0, 63, 1, 6);   // phase 60, stages last half
  PHASE(1, 0, 0, 3);    // phase 61: halves 62,63 may be in flight; need 62
  PHASE(2, 0, 0, 0);    // phase 62: need 63
  PHASE(3, 0, 0, 63);   // phase 63: nothing outstanding
#undef PHASE

  const int b = row0 >> 11, sbase = row0 & 2047;

  if (OUTP) {
#pragma unroll
    for (int i = 0; i < 4; i++)
#pragma unroll
      for (int j = 0; j < 4; j++)
#pragma unroll
        for (int r = 0; r < 4; r++) {
          int row = row0 + wm * 64 + i * 16 + (lane >> 4) * 4 + r;
          int col = col0 + wn * 32 + (j & 1) * 16 + (j >> 1) * 64 + (lane & 15);
          of[(size_t)row * 2048 + col] = acc[i][j][r];
        }
  } else if (proj < 2) {
    // RoPE epilogue: d in [0,64), partner acc[i][j+2]
    f16* dst = proj ? kb : qb;
    const int h = col0 >> 7;
#pragma unroll
    for (int i = 0; i < 4; i++)
#pragma unroll
      for (int jj = 0; jj < 2; jj++)
#pragma unroll
        for (int r = 0; r < 4; r++) {
          int s = sbase + wm * 64 + i * 16 + (lane >> 4) * 4 + r;
          int d = wn * 32 + jj * 16 + (lane & 15);
          float cv = cost[s * 64 + d], sv = sint[s * 64 + d];
          float x1 = acc[i][jj][r], x2 = acc[i][jj + 2][r];
          size_t base = ((size_t)(b * NH + h) * S_CTX + s) << 7;
          dst[base + d]      = (f16)(x1 * cv - x2 * sv);
          dst[base + d + 64] = (f16)(x2 * cv + x1 * sv);
        }
  } else {
    // V^T epilogue: [256 s][128 d] -> vtb[b,h,d,s] via LDS (f16x4 units, XOR swz)
    const int h = col0 >> 7;
    f16x4* ldsv = (f16x4*)lds;
#pragma unroll
    for (int i = 0; i < 4; i++)
#pragma unroll
      for (int j = 0; j < 4; j++) {
        f16x4 v;
#pragma unroll
        for (int r = 0; r < 4; r++) v[r] = (f16)acc[i][j][r];
        int su = wm * 16 + i * 4 + (lane >> 4);                         // s/4
        int d  = wn * 32 + (j & 1) * 16 + (j >> 1) * 64 + (lane & 15);
        ldsv[d * 64 + (su ^ ((d << 1) & 63))] = v;
      }
    __syncthreads();
#pragma unroll
    for (int it = 0; it < 8; ++it) {
      int o = it * 512 + tid;          // [0,4096): d = o>>5, c = o&31
      int d = o >> 5, c = o & 31;
      int xc = (d << 1) & 63;
      f16x4 lo = ldsv[d * 64 + ((2 * c) ^ xc)];
      f16x4 hi = ldsv[d * 64 + ((2 * c + 1) ^ xc)];
      f16x8 vv;
      vv[0] = lo[0]; vv[1] = lo[1]; vv[2] = lo[2]; vv[3] = lo[3];
      vv[4] = hi[0]; vv[5] = hi[1]; vv[6] = hi[2]; vv[7] = hi[3];
      *(f16x8*)&vtb[((size_t)(b * NH + h) * DH + d) * S_CTX + sbase + c * 8] = vv;
    }
  }
#undef RING_A
#undef RING_B
}

// ---------- flash attention, causal, no score scaling ----------
// grid: (16 tile-pairs, 32 bh). Block: 4 waves, each owns 16 q rows. KVBLK=64.
// Block i handles qt=i then qt=31-i -> every block does exactly 33 KV iterations.
__global__ __launch_bounds__(256)
void attn_k(const f16* __restrict__ q, const f16* __restrict__ kk,
            const f16* __restrict__ vt, f16* __restrict__ ctx) {
  __shared__ __align__(16) f16 Ks[64 * 128];   // [kv][d], slot ^= kv&7
  __shared__ __align__(16) f16 Vs[128 * 64];   // [d][kv], slot ^= d&7
  __shared__ __align__(16) f16 Pl[4][16 * 64]; // per wave [qr][kv], slot ^= qr&7
  const int tid = threadIdx.x, lane = tid & 63, wv = tid >> 6;
  const int bh = blockIdx.y;
  const int b = bh >> 4, h = bh & 15;
  const size_t plane = (size_t)bh * (S_CTX * DH);
  const f16* Qp = q + plane;
  const f16* Kp = kk + plane;
  const f16* Vp = vt + plane;
  const float LOG2E = 1.4426950408889634f;

  for (int half = 0; half < 2; half++) {
    const int qt = half ? (31 - (int)blockIdx.x) : (int)blockIdx.x;
    const int q0 = qt * 64;

    f16x8 qf[4];
    {
      const f16* qq = Qp + (size_t)(q0 + wv * 16 + (lane & 15)) * DH + ((lane >> 4) * 8);
#pragma unroll
      for (int ks = 0; ks < 4; ks++) {
        qf[ks] = *(const f16x8*)(qq + ks * 32);
#pragma unroll
        for (int e = 0; e < 8; e++) qf[ks][e] = (f16)((float)qf[ks][e] * LOG2E);
      }
    }
    float m_[4], l_[4];
    f32x4 o[8] = {};
#pragma unroll
    for (int r = 0; r < 4; r++) { m_[r] = -3e38f; l_[r] = 0.f; }

    for (int t = 0; t <= qt; t++) {
      __syncthreads();
#pragma unroll
      for (int j = 0; j < 4; j++) {
        int c = tid + j * 256;
        int row = c >> 4, sl = (c & 15) ^ (row & 7);
        gload16(Kp + (size_t)(t * 64 + row) * DH + sl * 8, Ks + c * 8);
      }
#pragma unroll
      for (int j = 0; j < 4; j++) {
        int c = tid + j * 256;
        int row = c >> 3, sl = (c & 7) ^ (row & 7);
        gload16(Vp + (size_t)row * S_CTX + t * 64 + sl * 8, Vs + c * 8);
      }
      __syncthreads();

      f32x4 st[4] = {};
#pragma unroll
      for (int n = 0; n < 4; n++) {
        int rK = n * 16 + (lane & 15);
#pragma unroll
        for (int ks = 0; ks < 4; ks++) {
          int slot = ks * 4 + (lane >> 4);
          f16x8 kf = *(const f16x8*)&Ks[rK * 128 + ((slot ^ (rK & 7)) << 3)];
          st[n] = __builtin_amdgcn_mfma_f32_16x16x32_f16(qf[ks], kf, st[n], 0, 0, 0);
        }
      }
      if (t == qt) {
#pragma unroll
        for (int n = 0; n < 4; n++)
#pragma unroll
          for (int r = 0; r < 4; r++) {
            int kvc = n * 16 + (lane & 15);
            int qr = wv * 16 + (lane >> 4) * 4 + r;
            if (kvc > qr) st[n][r] = -3e38f;
          }
      }
      float mx[4];
#pragma unroll
      for (int r = 0; r < 4; r++)
        mx[r] = fmaxf(fmaxf(st[0][r], st[1][r]), fmaxf(st[2][r], st[3][r]));
#pragma unroll
      for (int msk = 1; msk < 16; msk <<= 1)
#pragma unroll
        for (int r = 0; r < 4; r++) mx[r] = fmaxf(mx[r], __shfl_xor(mx[r], msk));
      bool need = false;
#pragma unroll
      for (int r = 0; r < 4; r++) need = need || (mx[r] > m_[r] + 8.0f);
      if (__any(need)) {
#pragma unroll
        for (int r = 0; r < 4; r++) {
          float nm = fmaxf(m_[r], mx[r]);
          float al = __builtin_amdgcn_exp2f(m_[r] - nm);
          m_[r] = nm;
          l_[r] *= al;
#pragma unroll
          for (int j = 0; j < 8; j++) o[j][r] *= al;
        }
      }
      float ps[4] = {0.f, 0.f, 0.f, 0.f};
      float pvv[4][4];
#pragma unroll
      for (int n = 0; n < 4; n++)
#pragma unroll
        for (int r = 0; r < 4; r++) {
          float p = __builtin_amdgcn_exp2f(st[n][r] - m_[r]);
          pvv[n][r] = p; ps[r] += p;
        }
#pragma unroll
      for (int msk = 1; msk < 16; msk <<= 1)
#pragma unroll
        for (int r = 0; r < 4; r++) ps[r] += __shfl_xor(ps[r], msk);
#pragma unroll
      for (int r = 0; r < 4; r++) l_[r] += ps[r];

      f16* Pw = Pl[wv];
#pragma unroll
      for (int n = 0; n < 4; n++)
#pragma unroll
        for (int r = 0; r < 4; r++) {
          int rowp = (lane >> 4) * 4 + r;
          int colp = n * 16 + (lane & 15);
          Pw[rowp * 64 + (((colp >> 3) ^ (rowp & 7)) << 3) + (colp & 7)] = (f16)pvv[n][r];
        }
#pragma unroll
      for (int ks = 0; ks < 2; ks++) {
        int rowp = lane & 15;
        int slotp = ks * 4 + (lane >> 4);
        f16x8 pa = *(const f16x8*)&Pw[rowp * 64 + ((slotp ^ (rowp & 7)) << 3)];
#pragma unroll
        for (int j = 0; j < 8; j++) {
          int rv = j * 16 + (lane & 15);
          int slotv = ks * 4 + (lane >> 4);
          f16x8 vf = *(const f16x8*)&Vs[rv * 64 + ((slotv ^ (rv & 7)) << 3)];
          o[j] = __builtin_amdgcn_mfma_f32_16x16x32_f16(pa, vf, o[j], 0, 0, 0);
        }
      }
    }

#pragma unroll
    for (int j = 0; j < 8; j++)
#pragma unroll
      for (int r = 0; r < 4; r++) {
        int qr = q0 + wv * 16 + (lane >> 4) * 4 + r;
        int dd = h * 128 + j * 16 + (lane & 15);
        ctx[((size_t)(b * S_CTX + qr) * 2048) + dd] = (f16)(o[j][r] / l_[r]);
      }
  }
}

extern "C" void kernel_launch(void* const* d_in, const int* in_sizes, int n_in,
                              void* d_out, int out_size, void* d_ws, size_t ws_size,
                              hipStream_t stream) {
  (void)in_sizes; (void)n_in; (void)out_size; (void)ws_size;
  const float* x  = (const float*)d_in[0];
  const float* Wq = (const float*)d_in[1];
  const float* Wk = (const float*)d_in[2];
  const float* Wv = (const float*)d_in[3];
  const float* Wo = (const float*)d_in[4];
  float* out = (float*)d_out;
  char* ws = (char*)d_ws;

  f16*   xb   = (f16*)(ws);                    // x fp16 [4096][2048]
  f16*   ctxb = (f16*)(ws);                    // reuse (xb dead after QKV)
  f16*   wqT  = (f16*)(ws + 16777216);         // [n][k] fp16, 8 MB each
  f16*   wkT  = (f16*)(ws + 25165824);
  f16*   wvT  = (f16*)(ws + 33554432);
  f16*   woT  = (f16*)(ws + 41943040);
  f16*   qb   = (f16*)(ws + 50331648);         // [b,h,s,d] fp16 (rope applied)
  f16*   kb   = (f16*)(ws + 67108864);
  f16*   vtb  = (f16*)(ws + 83886080);         // [b,h,d,s] fp16
  float* sint = (float*)(ws + 100663296);      // [2048][64]
  float* cost = (float*)(ws + 101187584);

  prep<<<dim3(25088), dim3(256), 0, stream>>>(x, Wq, Wk, Wv, Wo, xb,
                                              wqT, wkT, wvT, woT, sint, cost);
  gemm8<false><<<dim3(48, 16), dim3(512), 98304, stream>>>(
      xb, wqT, wkT, wvT, qb, kb, vtb, nullptr, sint, cost);
  attn_k<<<dim3(16, 32), dim3(256), 0, stream>>>(qb, kb, vtb, ctxb);
  gemm8<true><<<dim3(16, 16), dim3(512), 98304, stream>>>(
      ctxb, woT, woT, woT, nullptr, nullptr, nullptr, out, nullptr, nullptr);
}

// Round 6
// 274.896 us; speedup vs baseline: 1.2881x; 1.0214x over previous
//
#include <hip/hip_runtime.h>
#include <cstdint>
#include <cstddef>

typedef _Float16 f16;
typedef _Float16 f16x8 __attribute__((ext_vector_type(8)));
typedef _Float16 f16x4 __attribute__((ext_vector_type(4)));
typedef float    f32x4 __attribute__((ext_vector_type(4)));

#define S_CTX 2048
#define NH 16
#define DH 128

#define BAR() asm volatile("s_barrier" ::: "memory")
#define VMW(n) asm volatile("s_waitcnt vmcnt(" #n ")" ::: "memory")

__device__ __forceinline__ void gload16(const void* g, void* l) {
  __builtin_amdgcn_global_load_lds(
      (const __attribute__((address_space(1))) void*)g,
      (__attribute__((address_space(3))) void*)l, 16, 0, 0);
}

// ---------- prep: rope tables + x->f16 + 4x weight transpose, one dispatch ----------
__global__ void prep(const float* __restrict__ x,
                     const float* __restrict__ w0, const float* __restrict__ w1,
                     const float* __restrict__ w2, const float* __restrict__ w3,
                     f16* __restrict__ xb,
                     f16* __restrict__ o0, f16* __restrict__ o1,
                     f16* __restrict__ o2, f16* __restrict__ o3,
                     float* __restrict__ sint, float* __restrict__ cost) {
  const int bid = blockIdx.x, tid = threadIdx.x;
  if (bid < 512) {                       // rope tables: 2048*64
    int idx = bid * 256 + tid;
    int j = idx & 63, s = idx >> 6;
    float invf = __expf(-(float)(2 * j) * (1.0f / 128.0f) * 9.210340371976184f);
    float a = (float)s * invf;
    sint[idx] = sinf(a);
    cost[idx] = cosf(a);
  } else if (bid < 8704) {               // x fp32 -> fp16
    int i = ((bid - 512) * 256 + tid) * 4;
    float4 v = *(const float4*)(x + i);
    f16x4 o; o[0] = (f16)v.x; o[1] = (f16)v.y; o[2] = (f16)v.z; o[3] = (f16)v.w;
    *(f16x4*)(xb + i) = o;
  } else {                               // W[k][n] fp32 -> Wt[n][k] fp16
    int b2 = bid - 8704;
    int z = b2 >> 12, rem = b2 & 4095;
    int by = rem >> 6, bx = rem & 63;
    int tx = tid & 31, ty = tid >> 5;
    const float* in; f16* out;
    switch (z) {
      case 0: in = w0; out = o0; break;
      case 1: in = w1; out = o1; break;
      case 2: in = w2; out = o2; break;
      default: in = w3; out = o3; break;
    }
    __shared__ float tl[32][33];
    int xc = bx * 32 + tx, yc = by * 32 + ty;
#pragma unroll
    for (int r = 0; r < 32; r += 8)
      tl[ty + r][tx] = in[(size_t)(yc + r) * 2048 + xc];
    __syncthreads();
    int xo = by * 32 + tx, yo = bx * 32 + ty;
#pragma unroll
    for (int r = 0; r < 32; r += 8)
      out[(size_t)(yo + r) * 2048 + xo] = (f16)tl[tx][ty + r];
  }
}

// ---------- Q+K fused GEMM: 256^2 tile, 8 waves (2M x 4N), per-wave 128x64 ----------
// grid (16,16): gcol = bx*256 in [0,4096); proj = gcol>>11 (0=Q,1=K). 256 blocks = 1 round.
// K in 64 halves of 32. Ring depth-3 x (A 16KB + B 16KB) = 96 KB. 4 loads/thr/half,
// stage-ahead-2, counted vmcnt(4) (half p+1 proven landed each phase; tail 4/4/0/nop).
// 32 MFMA per barrier-pair (0.375 ds_reads/MFMA). Per-wave cols: (wn>>1)*128 +
// (wn&1)*32 + (j&1)*16 + (j>>1)*64 -> RoPE pair (d,d+64) = acc[i][j]/acc[i][j+2].
__global__ __launch_bounds__(512, 1)
void gemm_qk(const f16* __restrict__ A, const f16* __restrict__ wqT,
             const f16* __restrict__ wkT,
             f16* __restrict__ qb, f16* __restrict__ kb,
             const float* __restrict__ sint, const float* __restrict__ cost) {
  extern __shared__ __align__(16) char lds[];
  const int tid = threadIdx.x, lane = tid & 63;
  const int wvi = tid >> 6, wm = wvi >> 2, wn = wvi & 3;
  const int gcol = blockIdx.x * 256;
  const int proj = gcol >> 11;
  const int col0 = gcol & 2047;
  const int row0 = blockIdx.y * 256;
  const f16* Bt = proj ? wkT : wqT;

  const int ca0 = tid, ca1 = tid + 512;
  const int ra0 = ca0 >> 2, ra1 = ca1 >> 2;
  const int sa0 = (ca0 & 3) ^ ((ra0 >> 1) & 3);
  const int sa1 = (ca1 & 3) ^ ((ra1 >> 1) & 3);
  const f16* gA0 = A + (size_t)(row0 + ra0) * 2048 + sa0 * 8;
  const f16* gA1 = A + (size_t)(row0 + ra1) * 2048 + sa1 * 8;
  const f16* gB0 = Bt + (size_t)(col0 + ra0) * 2048 + sa0 * 8;
  const f16* gB1 = Bt + (size_t)(col0 + ra1) * 2048 + sa1 * 8;

  const int kslot = lane >> 4;
  int aoff[8], boff[4];
#pragma unroll
  for (int i = 0; i < 8; i++) {
    int row = wm * 128 + i * 16 + (lane & 15);
    aoff[i] = row * 64 + ((kslot ^ ((row >> 1) & 3)) << 4);
  }
#pragma unroll
  for (int j = 0; j < 4; j++) {
    int rb = (wn >> 1) * 128 + (wn & 1) * 32 + (j & 1) * 16 + (j >> 1) * 64 + (lane & 15);
    boff[j] = rb * 64 + ((kslot ^ ((rb >> 1) & 3)) << 4);
  }

  f32x4 acc[8][4] = {};

#define QKPH(SLOT, HS, SSLOT, DOSTAGE, WN) do {                                \
    const char* As_ = lds + (SLOT) * 32768;                                    \
    const char* Bs_ = As_ + 16384;                                             \
    f16x8 af[8], bf[4];                                                        \
    _Pragma("unroll") for (int i_ = 0; i_ < 8; i_++)                           \
      af[i_] = *(const f16x8*)(As_ + aoff[i_]);                                \
    _Pragma("unroll") for (int j_ = 0; j_ < 4; j_++)                           \
      bf[j_] = *(const f16x8*)(Bs_ + boff[j_]);                                \
    if (DOSTAGE) {                                                             \
      char* dA = lds + (SSLOT) * 32768;                                        \
      gload16(gA0 + (HS) * 32, dA + ca0 * 16);                                 \
      gload16(gA1 + (HS) * 32, dA + ca1 * 16);                                 \
      gload16(gB0 + (HS) * 32, dA + 16384 + ca0 * 16);                         \
      gload16(gB1 + (HS) * 32, dA + 16384 + ca1 * 16);                         \
    }                                                                          \
    asm volatile("s_waitcnt vmcnt(" #WN ")" ::: "memory");                     \
    BAR();                                                                     \
    __builtin_amdgcn_s_setprio(1);                                             \
    _Pragma("unroll") for (int i_ = 0; i_ < 8; i_++)                           \
      _Pragma("unroll") for (int j_ = 0; j_ < 4; j_++)                         \
        acc[i_][j_] = __builtin_amdgcn_mfma_f32_16x16x32_f16(af[i_], bf[j_],   \
                                                             acc[i_][j_], 0, 0, 0); \
    __builtin_amdgcn_s_setprio(0);                                             \
    BAR();                                                                     \
  } while (0)

  // prologue: stage halves 0->slot0, 1->slot1 (8 loads); vmcnt(4) -> h0 landed
#pragma unroll
  for (int h = 0; h < 2; h++) {
    char* dA = lds + h * 32768;
    gload16(gA0 + h * 32, dA + ca0 * 16);
    gload16(gA1 + h * 32, dA + ca1 * 16);
    gload16(gB0 + h * 32, dA + 16384 + ca0 * 16);
    gload16(gB1 + h * 32, dA + 16384 + ca1 * 16);
  }
  VMW(4); BAR();

  for (int t = 0; t < 20; ++t) {
    const int hb = 3 * t;
    QKPH(0, hb + 2, 2, 1, 4);
    QKPH(1, hb + 3, 0, 1, 4);
    QKPH(2, hb + 4, 1, 1, 4);
  }
  QKPH(0, 62, 2, 1, 4);   // phase 60
  QKPH(1, 63, 0, 1, 4);   // phase 61
  QKPH(2, 0, 0, 0, 0);    // phase 62: drain, h63 landed
  QKPH(0, 0, 0, 0, 63);   // phase 63
#undef QKPH

  // RoPE epilogue
  const int b = row0 >> 11, sb = row0 & 2047;
  f16* dst = proj ? kb : qb;
  const int h = (col0 >> 7) + (wn >> 1);
#pragma unroll
  for (int i = 0; i < 8; i++)
#pragma unroll
    for (int jj = 0; jj < 2; jj++)
#pragma unroll
      for (int r = 0; r < 4; r++) {
        int s = sb + wm * 128 + i * 16 + (lane >> 4) * 4 + r;
        int d = (wn & 1) * 32 + jj * 16 + (lane & 15);
        float cv = cost[s * 64 + d], sv = sint[s * 64 + d];
        float x1 = acc[i][jj][r], x2 = acc[i][jj + 2][r];
        size_t base = ((size_t)(b * NH + h) * S_CTX + s) << 7;
        dst[base + d]      = (f16)(x1 * cv - x2 * sv);
        dst[base + d + 64] = (f16)(x2 * cv + x1 * sv);
      }
}

// ---------- 8-phase GEMM, tile 256x128 (R5-proven): MODE 1 = V^T epi, MODE 2 = f32 epi
template<int MODE>
__global__ __launch_bounds__(512, 1)
void gemm8(const f16* __restrict__ A, const f16* __restrict__ Bt,
           f16* __restrict__ vtb, float* __restrict__ of) {
  extern __shared__ __align__(16) char lds[];
#define RING_A(e) (lds + (e) * 16384)
#define RING_B(e) (lds + 65536 + (e) * 8192)
  const int tid = threadIdx.x, lane = tid & 63;
  const int wvi = tid >> 6, wm = wvi >> 1, wn = wvi & 1;
  const int col0 = blockIdx.x * 128;
  const int row0 = blockIdx.y * 256;

  const int ca0 = tid, ca1 = tid + 512, cb0 = tid;
  const int rAs0 = ca0 >> 2, rAs1 = ca1 >> 2, rBs0 = cb0 >> 2;
  const int sA0 = (ca0 & 3) ^ ((rAs0 >> 1) & 3);
  const int sA1 = (ca1 & 3) ^ ((rAs1 >> 1) & 3);
  const int sB0 = (cb0 & 3) ^ ((rBs0 >> 1) & 3);
  const f16* gA0 = A + (size_t)(row0 + rAs0) * 2048 + sA0 * 8;
  const f16* gA1 = A + (size_t)(row0 + rAs1) * 2048 + sA1 * 8;
  const f16* gB0 = Bt + (size_t)(col0 + rBs0) * 2048 + sB0 * 8;

  const int kslot = lane >> 4;
  int aoff[4], boff[4];
#pragma unroll
  for (int i = 0; i < 4; i++) {
    int row = wm * 64 + i * 16 + (lane & 15);
    aoff[i] = row * 64 + ((kslot ^ ((row >> 1) & 3)) << 4);
  }
#pragma unroll
  for (int j = 0; j < 4; j++) {
    int rb = wn * 32 + (j & 1) * 16 + (j >> 1) * 64 + (lane & 15);
    boff[j] = rb * 64 + ((kslot ^ ((rb >> 1) & 3)) << 4);
  }

  f32x4 acc[4][4] = {};

#define PH8(SLOT, HS, DOSTAGE, WN) do {                                        \
    const char* As_ = RING_A(SLOT);                                            \
    const char* Bs_ = RING_B(SLOT);                                            \
    f16x8 af[4], bf[4];                                                        \
    _Pragma("unroll") for (int i_ = 0; i_ < 4; i_++)                           \
      af[i_] = *(const f16x8*)(As_ + aoff[i_]);                                \
    _Pragma("unroll") for (int j_ = 0; j_ < 4; j_++)                           \
      bf[j_] = *(const f16x8*)(Bs_ + boff[j_]);                                \
    if (DOSTAGE) {                                                             \
      gload16(gA0 + (HS) * 32, RING_A((HS) & 3) + ca0 * 16);                   \
      gload16(gA1 + (HS) * 32, RING_A((HS) & 3) + ca1 * 16);                   \
      gload16(gB0 + (HS) * 32, RING_B((HS) & 3) + cb0 * 16);                   \
    }                                                                          \
    asm volatile("s_waitcnt vmcnt(" #WN ")" ::: "memory");                     \
    BAR();                                                                     \
    __builtin_amdgcn_s_setprio(1);                                             \
    _Pragma("unroll") for (int i_ = 0; i_ < 4; i_++)                           \
      _Pragma("unroll") for (int j_ = 0; j_ < 4; j_++)                         \
        acc[i_][j_] = __builtin_amdgcn_mfma_f32_16x16x32_f16(af[i_], bf[j_],   \
                                                             acc[i_][j_], 0, 0, 0); \
    __builtin_amdgcn_s_setprio(0);                                             \
    BAR();                                                                     \
  } while (0)

#pragma unroll
  for (int h = 0; h < 3; h++) {
    gload16(gA0 + h * 32, RING_A(h) + ca0 * 16);
    gload16(gA1 + h * 32, RING_A(h) + ca1 * 16);
    gload16(gB0 + h * 32, RING_B(h) + cb0 * 16);
  }
  VMW(6); BAR();

  for (int t = 0; t < 15; ++t) {
    const int p = t * 4;
    PH8(0, p + 3, 1, 6);
    PH8(1, p + 4, 1, 6);
    PH8(2, p + 5, 1, 6);
    PH8(3, p + 6, 1, 6);
  }
  PH8(0, 63, 1, 6);
  PH8(1, 0, 0, 3);
  PH8(2, 0, 0, 0);
  PH8(3, 0, 0, 63);
#undef PH8

  const int b = row0 >> 11, sbase = row0 & 2047;

  if (MODE == 2) {
#pragma unroll
    for (int i = 0; i < 4; i++)
#pragma unroll
      for (int j = 0; j < 4; j++)
#pragma unroll
        for (int r = 0; r < 4; r++) {
          int row = row0 + wm * 64 + i * 16 + (lane >> 4) * 4 + r;
          int col = col0 + wn * 32 + (j & 1) * 16 + (j >> 1) * 64 + (lane & 15);
          of[(size_t)row * 2048 + col] = acc[i][j][r];
        }
  } else {
    // V^T epilogue: [256 s][128 d] -> vtb[b,h,d,s] via LDS (f16x4 units, XOR swz)
    const int h = col0 >> 7;
    f16x4* ldsv = (f16x4*)lds;
#pragma unroll
    for (int i = 0; i < 4; i++)
#pragma unroll
      for (int j = 0; j < 4; j++) {
        f16x4 v;
#pragma unroll
        for (int r = 0; r < 4; r++) v[r] = (f16)acc[i][j][r];
        int su = wm * 16 + i * 4 + (lane >> 4);
        int d  = wn * 32 + (j & 1) * 16 + (j >> 1) * 64 + (lane & 15);
        ldsv[d * 64 + (su ^ ((d << 1) & 63))] = v;
      }
    __syncthreads();
#pragma unroll
    for (int it = 0; it < 8; ++it) {
      int o = it * 512 + tid;
      int d = o >> 5, c = o & 31;
      int xc = (d << 1) & 63;
      f16x4 lo = ldsv[d * 64 + ((2 * c) ^ xc)];
      f16x4 hi = ldsv[d * 64 + ((2 * c + 1) ^ xc)];
      f16x8 vv;
      vv[0] = lo[0]; vv[1] = lo[1]; vv[2] = lo[2]; vv[3] = lo[3];
      vv[4] = hi[0]; vv[5] = hi[1]; vv[6] = hi[2]; vv[7] = hi[3];
      *(f16x8*)&vtb[((size_t)(b * NH + h) * DH + d) * S_CTX + sbase + c * 8] = vv;
    }
  }
#undef RING_A
#undef RING_B
}

// ---------- flash attention: 8 waves, 128-row q-tiles, K/V double-buffered ----------
// grid (8, 32). Block bx handles q128-tile bx then 15-bx -> 34 uniform KV64 iters.
// Per tile: issue stage(t+1) into buf^1 FIRST, compute on buf (QK^T, online softmax,
// PV), then one vmcnt(0)+s_barrier (T3 minimum-2-phase; HBM hides under compute).
__global__ __launch_bounds__(512)
void attn_k(const f16* __restrict__ q, const f16* __restrict__ kk,
            const f16* __restrict__ vt, f16* __restrict__ ctx) {
  __shared__ __align__(16) f16 Ks[2][64 * 128];   // [kv][d], slot ^= kv&7
  __shared__ __align__(16) f16 Vs[2][128 * 64];   // [d][kv], slot ^= d&7
  __shared__ __align__(16) f16 Pl[8][16 * 64];    // per wave [qr][kv], slot ^= qr&7
  const int tid = threadIdx.x, lane = tid & 63, wv = tid >> 6;
  const int bh = blockIdx.y;
  const int b = bh >> 4, h = bh & 15;
  const size_t plane = (size_t)bh * (S_CTX * DH);
  const f16* Qp = q + plane;
  const f16* Kp = kk + plane;
  const f16* Vp = vt + plane;
  const float LOG2E = 1.4426950408889634f;

  // staging addr constants (512 threads, 2 chunks each for K and V)
  const int ck0 = tid, ck1 = tid + 512;           // K: row = c>>4, slot = c&15
  const int cv0 = tid, cv1 = tid + 512;           // V: row = c>>3, slot = c&7

  for (int half = 0; half < 2; half++) {
    const int Q = half ? (15 - (int)blockIdx.x) : (int)blockIdx.x;
    const int q0 = Q * 128;
    const int NT = 2 * Q + 2;

    // Q fragments (rows q0 + wv*16 .. +15), pre-scaled by log2(e)
    f16x8 qf[4];
    {
      const f16* qq = Qp + (size_t)(q0 + wv * 16 + (lane & 15)) * DH + ((lane >> 4) * 8);
#pragma unroll
      for (int ks = 0; ks < 4; ks++) {
        qf[ks] = *(const f16x8*)(qq + ks * 32);
#pragma unroll
        for (int e = 0; e < 8; e++) qf[ks][e] = (f16)((float)qf[ks][e] * LOG2E);
      }
    }
    float m_[4], l_[4];
    f32x4 o[8] = {};
#pragma unroll
    for (int r = 0; r < 4; r++) { m_[r] = -3e38f; l_[r] = 0.f; }

    // prologue: stage tile 0 -> buf 0
    {
      int rk0 = ck0 >> 4, rk1 = ck1 >> 4;
      gload16(Kp + (size_t)rk0 * DH + (((ck0 & 15) ^ (rk0 & 7)) * 8), &Ks[0][ck0 * 8]);
      gload16(Kp + (size_t)rk1 * DH + (((ck1 & 15) ^ (rk1 & 7)) * 8), &Ks[0][ck1 * 8]);
      int rv0 = cv0 >> 3, rv1 = cv1 >> 3;
      gload16(Vp + (size_t)rv0 * S_CTX + (((cv0 & 7) ^ (rv0 & 7)) * 8), &Vs[0][cv0 * 8]);
      gload16(Vp + (size_t)rv1 * S_CTX + (((cv1 & 7) ^ (rv1 & 7)) * 8), &Vs[0][cv1 * 8]);
    }
    VMW(0); BAR();

    int cur = 0;
    for (int t = 0; t < NT; t++) {
      // issue next-tile stage early (lands during compute)
      if (t + 1 < NT) {
        const f16* Kt = Kp + (size_t)(t + 1) * 64 * DH;
        const f16* Vt = Vp + (size_t)(t + 1) * 64;
        int nb = cur ^ 1;
        int rk0 = ck0 >> 4, rk1 = ck1 >> 4;
        gload16(Kt + (size_t)rk0 * DH + (((ck0 & 15) ^ (rk0 & 7)) * 8), &Ks[nb][ck0 * 8]);
        gload16(Kt + (size_t)rk1 * DH + (((ck1 & 15) ^ (rk1 & 7)) * 8), &Ks[nb][ck1 * 8]);
        int rv0 = cv0 >> 3, rv1 = cv1 >> 3;
        gload16(Vt + (size_t)rv0 * S_CTX + (((cv0 & 7) ^ (rv0 & 7)) * 8), &Vs[nb][cv0 * 8]);
        gload16(Vt + (size_t)rv1 * S_CTX + (((cv1 & 7) ^ (rv1 & 7)) * 8), &Vs[nb][cv1 * 8]);
      }

      const f16* Ksc = Ks[cur];
      const f16* Vsc = Vs[cur];

      // S = Q K^T (log2-units)
      f32x4 st[4] = {};
#pragma unroll
      for (int n = 0; n < 4; n++) {
        int rK = n * 16 + (lane & 15);
#pragma unroll
        for (int ks = 0; ks < 4; ks++) {
          int slot = ks * 4 + (lane >> 4);
          f16x8 kf = *(const f16x8*)&Ksc[rK * 128 + ((slot ^ (rK & 7)) << 3)];
          st[n] = __builtin_amdgcn_mfma_f32_16x16x32_f16(qf[ks], kf, st[n], 0, 0, 0);
        }
      }
      // causal mask (diagonal band spans tiles 2Q and 2Q+1)
      if (t >= 2 * Q) {
#pragma unroll
        for (int n = 0; n < 4; n++)
#pragma unroll
          for (int r = 0; r < 4; r++) {
            int kvc = t * 64 + n * 16 + (lane & 15);
            int qr = q0 + wv * 16 + (lane >> 4) * 4 + r;
            if (kvc > qr) st[n][r] = -3e38f;
          }
      }
      // online softmax (16-lane-group rows)
      float mx[4];
#pragma unroll
      for (int r = 0; r < 4; r++)
        mx[r] = fmaxf(fmaxf(st[0][r], st[1][r]), fmaxf(st[2][r], st[3][r]));
#pragma unroll
      for (int msk = 1; msk < 16; msk <<= 1)
#pragma unroll
        for (int r = 0; r < 4; r++) mx[r] = fmaxf(mx[r], __shfl_xor(mx[r], msk));
      bool need = false;
#pragma unroll
      for (int r = 0; r < 4; r++) need = need || (mx[r] > m_[r] + 8.0f);
      if (__any(need)) {
#pragma unroll
        for (int r = 0; r < 4; r++) {
          float nm = fmaxf(m_[r], mx[r]);
          float al = __builtin_amdgcn_exp2f(m_[r] - nm);
          m_[r] = nm;
          l_[r] *= al;
#pragma unroll
          for (int j = 0; j < 8; j++) o[j][r] *= al;
        }
      }
      float ps[4] = {0.f, 0.f, 0.f, 0.f};
      float pvv[4][4];
#pragma unroll
      for (int n = 0; n < 4; n++)
#pragma unroll
        for (int r = 0; r < 4; r++) {
          float p = __builtin_amdgcn_exp2f(st[n][r] - m_[r]);
          pvv[n][r] = p; ps[r] += p;
        }
#pragma unroll
      for (int msk = 1; msk < 16; msk <<= 1)
#pragma unroll
        for (int r = 0; r < 4; r++) ps[r] += __shfl_xor(ps[r], msk);
#pragma unroll
      for (int r = 0; r < 4; r++) l_[r] += ps[r];

      // P -> per-wave LDS (C-layout -> A-frag layout)
      f16* Pw = Pl[wv];
#pragma unroll
      for (int n = 0; n < 4; n++)
#pragma unroll
        for (int r = 0; r < 4; r++) {
          int rowp = (lane >> 4) * 4 + r;
          int colp = n * 16 + (lane & 15);
          Pw[rowp * 64 + (((colp >> 3) ^ (rowp & 7)) << 3) + (colp & 7)] = (f16)pvv[n][r];
        }
      // O += P V
#pragma unroll
      for (int ks = 0; ks < 2; ks++) {
        int rowp = lane & 15;
        int slotp = ks * 4 + (lane >> 4);
        f16x8 pa = *(const f16x8*)&Pw[rowp * 64 + ((slotp ^ (rowp & 7)) << 3)];
#pragma unroll
        for (int j = 0; j < 8; j++) {
          int rv = j * 16 + (lane & 15);
          int slotv = ks * 4 + (lane >> 4);
          f16x8 vf = *(const f16x8*)&Vsc[rv * 64 + ((slotv ^ (rv & 7)) << 3)];
          o[j] = __builtin_amdgcn_mfma_f32_16x16x32_f16(pa, vf, o[j], 0, 0, 0);
        }
      }

      VMW(0); BAR();       // next tile fully staged; all waves past reads of buf^1
      cur ^= 1;
    }

#pragma unroll
    for (int j = 0; j < 8; j++)
#pragma unroll
      for (int r = 0; r < 4; r++) {
        int qr = q0 + wv * 16 + (lane >> 4) * 4 + r;
        int dd = h * 128 + j * 16 + (lane & 15);
        ctx[((size_t)(b * S_CTX + qr) * 2048) + dd] = (f16)(o[j][r] / l_[r]);
      }
  }
}

extern "C" void kernel_launch(void* const* d_in, const int* in_sizes, int n_in,
                              void* d_out, int out_size, void* d_ws, size_t ws_size,
                              hipStream_t stream) {
  (void)in_sizes; (void)n_in; (void)out_size; (void)ws_size;
  const float* x  = (const float*)d_in[0];
  const float* Wq = (const float*)d_in[1];
  const float* Wk = (const float*)d_in[2];
  const float* Wv = (const float*)d_in[3];
  const float* Wo = (const float*)d_in[4];
  float* out = (float*)d_out;
  char* ws = (char*)d_ws;

  f16*   xb   = (f16*)(ws);                    // x fp16 [4096][2048]
  f16*   ctxb = (f16*)(ws);                    // reuse (xb dead after QKV)
  f16*   wqT  = (f16*)(ws + 16777216);         // [n][k] fp16, 8 MB each
  f16*   wkT  = (f16*)(ws + 25165824);
  f16*   wvT  = (f16*)(ws + 33554432);
  f16*   woT  = (f16*)(ws + 41943040);
  f16*   qb   = (f16*)(ws + 50331648);         // [b,h,s,d] fp16 (rope applied)
  f16*   kb   = (f16*)(ws + 67108864);
  f16*   vtb  = (f16*)(ws + 83886080);         // [b,h,d,s] fp16
  float* sint = (float*)(ws + 100663296);      // [2048][64]
  float* cost = (float*)(ws + 101187584);

  prep<<<dim3(25088), dim3(256), 0, stream>>>(x, Wq, Wk, Wv, Wo, xb,
                                              wqT, wkT, wvT, woT, sint, cost);
  gemm_qk<<<dim3(16, 16), dim3(512), 98304, stream>>>(xb, wqT, wkT, qb, kb, sint, cost);
  gemm8<1><<<dim3(16, 16), dim3(512), 98304, stream>>>(xb, wvT, vtb, nullptr);
  attn_k<<<dim3(8, 32), dim3(512), 0, stream>>>(qb, kb, vtb, ctxb);
  gemm8<2><<<dim3(16, 16), dim3(512), 98304, stream>>>(ctxb, woT, nullptr, out);
}